// Round 1
// 5009.813 us; speedup vs baseline: 1.2108x; 1.2108x over previous
//
#include <hip/hip_runtime.h>
#include <math.h>

// Greedy LSTM decoder, MI355X (gfx950).
// B=128, E=512, H=1024, V=32000, T=48 (47 compute steps).
//
// Accuracy strategy (unchanged from previous version):
//  - gates: bf16 3-way-split MFMA, 6 passes (error ~1e-6 rel, fp32-acc limited)
//  - logits: bf16 hi*hi single pass (abs err ~4e-3 << 1.57e-2 threshold)
//  - argmax: top-8 candidates from approx logits, re-scored with fp64 dots
//    against fp32 h and fp32 w_out -> fp64-exact token selection.
//
// Structure changes this round:
//  - k_gates + k_cell fused: 256 blocks x 4 waves (4 waves/CU -> full MFMA rate),
//    K-quartered per wave, LDS reduce + cell epilogue. No partials buffer.
//    xh is ping-ponged (kernel reads old h while writing new h).
//  - k_logits emits per-wave per-row top-2 candidates (2000/row) in epilogue.
//  - k_argmax scans the 16 KB candidate list instead of the 128 KB logit row.

typedef unsigned short u16;
typedef unsigned int u32;
typedef __bf16 bf16x8 __attribute__((ext_vector_type(8)));
typedef float f32x4 __attribute__((ext_vector_type(4)));

#define B_ 128
#define E_ 512
#define H_ 1024
#define V_ 32000
#define G4 4096
#define KX 1536  // E_ + H_
#define NC 2000  // candidates per row (250 blocks * 4 waves * top2)

__device__ __forceinline__ u16 f2bf(float f){
  u32 u = __float_as_uint(f);
  u32 r = (u + 0x7FFFu + ((u >> 16) & 1u)) >> 16;  // RNE
  return (u16)r;
}
__device__ __forceinline__ float bf2f(u16 s){ return __uint_as_float(((u32)s) << 16); }
__device__ __forceinline__ void split3(float x, u16 &a, u16 &b, u16 &c){
  a = f2bf(x); float r1 = x - bf2f(a);
  b = f2bf(r1); float r2 = r1 - bf2f(b);
  c = f2bf(r2);
}
__device__ __forceinline__ bf16x8 ldb8(const u16* p){ return *reinterpret_cast<const bf16x8*>(p); }
__device__ __forceinline__ f32x4 mf(bf16x8 a, bf16x8 b, f32x4 c){
  return __builtin_amdgcn_mfma_f32_16x16x32_bf16(a, b, c, 0, 0, 0);
}

// ---------------- precompute kernels ----------------

// zero out[t=0] slice: 4000*256 float4 == 128*32000 floats
__global__ void k_zero(float* __restrict__ p){
  const int i = blockIdx.x * 256 + threadIdx.x;
  reinterpret_cast<float4*>(p)[i] = make_float4(0.f, 0.f, 0.f, 0.f);
}

// w_out fp32 [V][H] -> bf16 hi [V][H]
__global__ void k_wout(const float* __restrict__ w, u16* __restrict__ wo){
  const int i = blockIdx.x * 256 + threadIdx.x;  // 32000 blocks
  float4 v = reinterpret_cast<const float4*>(w)[i];
  ushort4 o;
  o.x = f2bf(v.x); o.y = f2bf(v.y); o.z = f2bf(v.z); o.w = f2bf(v.w);
  reinterpret_cast<ushort4*>(wo)[i] = o;
}

// W_cat[n][k] = [w_ih | w_hh], 3-way bf16 split.  grid (6, 4096)
__global__ void k_wc(const float* __restrict__ wih, const float* __restrict__ whh,
                     u16* __restrict__ ch, u16* __restrict__ cm, u16* __restrict__ cl){
  const int k = blockIdx.x * 256 + threadIdx.x;
  const int n = blockIdx.y;
  float v = (k < E_) ? wih[(size_t)n * E_ + k] : whh[(size_t)n * H_ + (k - E_)];
  u16 a, b, c; split3(v, a, b, c);
  const size_t o = (size_t)n * KX + k;
  ch[o] = a; cm[o] = b; cl[o] = c;
}

// xh(t=1) = [embedding[sos] | encoder_h], split.  grid (6, 128)
__global__ void k_xh0(const float* __restrict__ emb, const float* __restrict__ ench,
                      const int* __restrict__ sos,
                      u16* __restrict__ xh, u16* __restrict__ xm, u16* __restrict__ xl){
  const int k = blockIdx.x * 256 + threadIdx.x;
  const int m = blockIdx.y;
  float v = (k < E_) ? emb[(size_t)sos[0] * E_ + k] : ench[(size_t)m * H_ + (k - E_)];
  u16 a, b, c; split3(v, a, b, c);
  const int o = m * KX + k;
  xh[o] = a; xm[o] = b; xl[o] = c;
}

// c init = encoder_c.  grid 512
__global__ void k_c0(const float* __restrict__ src, float* __restrict__ dst){
  const int i = blockIdx.x * 256 + threadIdx.x;
  dst[i] = src[i];
}

// ---------------- per-step kernels ----------------

// Fused gates GEMM + LSTM cell.
// Grid 256 blocks x 256 thr (4 waves). Block: mb = bid&1 (64 batch rows),
// ub = bid>>1 (8 units, all 4 gates -> 32 output cols). Wave w = K-quarter.
// Per wave: 4 i-tiles x 2 col-tiles x 12 kc x 6 split-passes = 576 MFMA.
// Epilogue: LDS reduce of the 4 K-partials + bias + activations + c/h update,
// h splits written to the OTHER (ping-pong) xh buffer.
__global__ __launch_bounds__(256) void k_gates_cell(
    const u16* __restrict__ xh_h, const u16* __restrict__ xh_m, const u16* __restrict__ xh_l,
    const u16* __restrict__ wc_h, const u16* __restrict__ wc_m, const u16* __restrict__ wc_l,
    const float* __restrict__ bih, const float* __restrict__ bhh,
    float* __restrict__ c_f, float* __restrict__ h_f,
    u16* __restrict__ oh, u16* __restrict__ om, u16* __restrict__ ol){
  __shared__ float red[4][64 * 33];  // stride-33 pad, 33.8 KB
  const int tid = threadIdx.x;
  const int L = tid & 63, w = tid >> 6;
  const int l15 = L & 15, q = L >> 4;
  const int mb = (int)blockIdx.x & 1;
  const int ub = (int)blockIdx.x >> 1;

  const u16* pa[3] = { xh_h, xh_m, xh_l };
  const u16* pb[3] = { wc_h, wc_m, wc_l };

  f32x4 acc[4][2];
  const f32x4 z4 = {0.f, 0.f, 0.f, 0.f};
#pragma unroll
  for (int i = 0; i < 4; ++i){ acc[i][0] = z4; acc[i][1] = z4; }

  const int arow0 = mb * 64 + l15;
  // col-lane l15 of col-tile ct maps to gate g = ct*2 + (l15>>3), unit u = l15&7
  const size_t brow[2] = {
    (size_t)(((l15 >> 3)) * 1024 + ub * 8 + (l15 & 7)),
    (size_t)((2 + (l15 >> 3)) * 1024 + ub * 8 + (l15 & 7)) };
  const int kb = w * 384 + q * 8;

#pragma unroll 1
  for (int it = 0; it < 6; ++it){
#pragma unroll
    for (int kc = 0; kc < 2; ++kc){
      const int ko = kb + it * 64 + kc * 32;
      bf16x8 af[4][3], bfr[2][3];
#pragma unroll
      for (int i = 0; i < 4; ++i)
#pragma unroll
        for (int s = 0; s < 3; ++s)
          af[i][s] = ldb8(pa[s] + (size_t)(arow0 + i * 16) * KX + ko);
#pragma unroll
      for (int ct = 0; ct < 2; ++ct)
#pragma unroll
        for (int s = 0; s < 3; ++s)
          bfr[ct][s] = ldb8(pb[s] + brow[ct] * KX + ko);
#pragma unroll
      for (int i = 0; i < 4; ++i)
#pragma unroll
        for (int ct = 0; ct < 2; ++ct){
          f32x4 a_ = acc[i][ct];
          a_ = mf(af[i][0], bfr[ct][0], a_);  // hi*hi
          a_ = mf(af[i][0], bfr[ct][1], a_);  // hi*mid
          a_ = mf(af[i][1], bfr[ct][0], a_);  // mid*hi
          a_ = mf(af[i][0], bfr[ct][2], a_);  // hi*lo
          a_ = mf(af[i][1], bfr[ct][1], a_);  // mid*mid
          a_ = mf(af[i][2], bfr[ct][0], a_);  // lo*hi
          acc[i][ct] = a_;
        }
    }
  }
  // dump partials to LDS: row = local batch row (0..63), col = ct*16 + l15
#pragma unroll
  for (int i = 0; i < 4; ++i)
#pragma unroll
    for (int ct = 0; ct < 2; ++ct)
#pragma unroll
      for (int r = 0; r < 4; ++r)
        red[w][(i * 16 + q * 4 + r) * 33 + ct * 16 + l15] = acc[i][ct][r];
  __syncthreads();

  // cell: 512 outputs (64 rows x 8 units), 2 per thread
#pragma unroll
  for (int rep = 0; rep < 2; ++rep){
    const int idx = tid + rep * 256;
    const int ml = idx >> 3, uu = idx & 7;
    float gv[4];
#pragma unroll
    for (int g = 0; g < 4; ++g){
      const int c = (g >> 1) * 16 + ((g & 1) << 3) + uu;
      const float s = red[0][ml * 33 + c] + red[1][ml * 33 + c]
                    + red[2][ml * 33 + c] + red[3][ml * 33 + c];
      const int n = g * 1024 + ub * 8 + uu;
      gv[g] = s + bih[n] + bhh[n];
    }
    const float ig = 1.f / (1.f + expf(-gv[0]));
    const float fg = 1.f / (1.f + expf(-gv[1]));
    const float g2 = tanhf(gv[2]);
    const float og = 1.f / (1.f + expf(-gv[3]));
    const int mg = mb * 64 + ml, ug = ub * 8 + uu;
    const int ci_ = mg * H_ + ug;
    const float c = fg * c_f[ci_] + ig * g2;
    c_f[ci_] = c;
    const float h = og * tanhf(c);
    h_f[ci_] = h;
    u16 a, b, cc; split3(h, a, b, cc);
    const int o = mg * KX + E_ + ug;
    oh[o] = a; om[o] = b; ol[o] = cc;
  }
}

// logits: [128 x 1024](h_hi) * w_out_hi^T -> out[t].  grid 250 x 256thr.
// block tile 128x128; wave = 128m x 32n; A via LDS (pad 72), B direct global.
// Epilogue additionally emits per-wave per-row top-2 (val,idx) candidates.
__global__ __launch_bounds__(256) void k_logits(
    const u16* __restrict__ xh_h, const u16* __restrict__ wo,
    const float* __restrict__ bout, float* __restrict__ out,
    float2* __restrict__ cand, int t){
  __shared__ alignas(16) u16 lA[128 * 72];
  const int tid = threadIdx.x;
  const int L = tid & 63, wv = tid >> 6;
  const int l15 = L & 15, q = L >> 4;
  const int C0 = blockIdx.x * 128;

  f32x4 acc[8][2];
  const f32x4 z4 = {0.f, 0.f, 0.f, 0.f};
#pragma unroll
  for (int i = 0; i < 8; ++i){ acc[i][0] = z4; acc[i][1] = z4; }

  const u16* bptr0 = wo + (size_t)(C0 + wv * 32 + l15) * H_ + q * 8;
  const u16* bptr1 = bptr0 + (size_t)16 * H_;

#pragma unroll 1
  for (int it = 0; it < 16; ++it){
    const int k0 = it * 64;
#pragma unroll
    for (int s2 = 0; s2 < 4; ++s2){
      const int c = tid + 256 * s2;       // 0..1023 : 128 rows x 8 chunks
      const int row = c >> 3, ch = c & 7;
      *reinterpret_cast<uint4*>(&lA[row * 72 + ch * 8]) =
        *reinterpret_cast<const uint4*>(&xh_h[(size_t)row * KX + E_ + k0 + ch * 8]);
    }
    __syncthreads();
    const bf16x8 b00 = ldb8(bptr0 + k0);
    const bf16x8 b01 = ldb8(bptr0 + k0 + 32);
    const bf16x8 b10 = ldb8(bptr1 + k0);
    const bf16x8 b11 = ldb8(bptr1 + k0 + 32);
#pragma unroll
    for (int i = 0; i < 8; ++i){
      const bf16x8 a0 = ldb8(&lA[(i * 16 + l15) * 72 + q * 8]);
      const bf16x8 a1 = ldb8(&lA[(i * 16 + l15) * 72 + 32 + q * 8]);
      acc[i][0] = mf(a0, b00, acc[i][0]);
      acc[i][0] = mf(a1, b01, acc[i][0]);
      acc[i][1] = mf(a0, b10, acc[i][1]);
      acc[i][1] = mf(a1, b11, acc[i][1]);
    }
    __syncthreads();
  }
  const size_t ob = (size_t)t * B_ * V_;
  const int n0 = C0 + wv * 32 + l15;
  const float bo0 = bout[n0], bo1 = bout[n0 + 16];
  const int cw = (int)blockIdx.x * 4 + wv;   // 0..999
#pragma unroll
  for (int i = 0; i < 8; ++i)
#pragma unroll
    for (int r = 0; r < 4; ++r){
      const int m = i * 16 + q * 4 + r;
      const float va = acc[i][0][r] + bo0;
      const float vb = acc[i][1][r] + bo1;
      out[ob + (size_t)m * V_ + n0] = va;
      out[ob + (size_t)m * V_ + n0 + 16] = vb;
      // per-row top-2 over this wave's 32 cols (butterfly over 16 col-lanes)
      float v1, v2; int i1, i2;
      if (va >= vb){ v1 = va; i1 = n0;      v2 = vb; i2 = n0 + 16; }
      else         { v1 = vb; i1 = n0 + 16; v2 = va; i2 = n0; }
#pragma unroll
      for (int mm = 1; mm <= 8; mm <<= 1){
        const float ov1 = __shfl_xor(v1, mm), ov2 = __shfl_xor(v2, mm);
        const int   oi1 = __shfl_xor(i1, mm), oi2 = __shfl_xor(i2, mm);
        if (ov1 > v1){
          if (v1 >= ov2){ v2 = v1; i2 = i1; } else { v2 = ov2; i2 = oi2; }
          v1 = ov1; i1 = oi1;
        } else if (ov1 > v2){ v2 = ov1; i2 = oi1; }
      }
      if (l15 == 0){
        float2* crow = cand + (size_t)m * NC;
        crow[cw]        = make_float2(v1, __int_as_float(i1));
        crow[1000 + cw] = make_float2(v2, __int_as_float(i2));
      }
    }
}

// per-row argmax: scan 2000 candidates, top-8, fp64 refinement, embed gather.
// grid 128 (one block per batch row) x 256thr.
__global__ __launch_bounds__(256) void k_argmax(
    const float2* __restrict__ cand,
    const float* __restrict__ h_f, const float* __restrict__ w_out,
    const float* __restrict__ bout, const float* __restrict__ emb,
    u16* __restrict__ xh_h, u16* __restrict__ xh_m, u16* __restrict__ xh_l){
  __shared__ float cv[512];
  __shared__ int   ci[512];
  __shared__ int   sel_i[8];
  __shared__ double refv[8];
  __shared__ int   s_tok;
  const int m = blockIdx.x, tid = threadIdx.x;
  const float2* cr = cand + (size_t)m * NC;

  // per-thread top-2 over strided candidate slice
  float v1 = -1e38f, v2 = -1e38f; int i1 = 0, i2 = 0;
  for (int n = tid; n < NC; n += 256){
    const float2 e = cr[n];
    const float v = e.x; const int ii = __float_as_int(e.y);
    if (v > v1){ v2 = v1; i2 = i1; v1 = v; i1 = ii; }
    else if (v > v2){ v2 = v; i2 = ii; }
  }
  cv[tid] = v1; ci[tid] = i1; cv[256 + tid] = v2; ci[256 + tid] = i2;
  __syncthreads();

  // wave 0 extracts top-8 of the 512 candidates
  for (int s = 0; s < 8; ++s){
    if (tid < 64){
      float bv = -1e38f; int bp = 0;
#pragma unroll
      for (int qq = 0; qq < 8; ++qq){
        const int p = tid * 8 + qq;
        const float v = cv[p];
        if (v > bv){ bv = v; bp = p; }
      }
      for (int off = 32; off >= 1; off >>= 1){
        const float ov = __shfl_xor(bv, off);
        const int   op = __shfl_xor(bp, off);
        if (ov > bv || (ov == bv && op < bp)){ bv = ov; bp = op; }
      }
      if (tid == 0) sel_i[s] = ci[bp];
      if ((bp >> 3) == tid) cv[bp] = -1e38f;
    }
    __syncthreads();
  }

  // fp64 re-score of the 8 candidates: 32 lanes per candidate
  {
    const int wv = tid >> 6, L = tid & 63;
    const int c = wv * 2 + (L >> 5);
    const int kk = L & 31;
    const int idx = sel_i[c];
    const float* hr = h_f + (size_t)m * H_;
    const float* wr = w_out + (size_t)idx * H_;
    double a = 0.0;
#pragma unroll 4
    for (int qq = 0; qq < 32; ++qq){
      const int k = qq * 32 + kk;
      a += (double)hr[k] * (double)wr[k];
    }
    for (int off = 16; off >= 1; off >>= 1) a += __shfl_xor(a, off);
    if (kk == 0) refv[c] = a + (double)bout[idx];
  }
  __syncthreads();

  if (tid == 0){
    double bb = -1e300; int bi = 0x7fffffff;
#pragma unroll
    for (int c = 0; c < 8; ++c){
      const double v = refv[c]; const int idx = sel_i[c];
      if (v > bb || (v == bb && idx < bi)){ bb = v; bi = idx; }
    }
    s_tok = bi;
  }
  __syncthreads();

  const int tok = s_tok;
  for (int k = tid; k < E_; k += 256){
    const float v = emb[(size_t)tok * E_ + k];
    u16 a, b, c2; split3(v, a, b, c2);
    const int o = m * KX + k;
    xh_h[o] = a; xh_m[o] = b; xh_l[o] = c2;
  }
}

// ---------------- host ----------------

extern "C" void kernel_launch(void* const* d_in, const int* in_sizes, int n_in,
                              void* d_out, int out_size, void* d_ws, size_t ws_size,
                              hipStream_t stream){
  const float* enc_h = (const float*)d_in[0];
  const float* enc_c = (const float*)d_in[1];
  const float* emb   = (const float*)d_in[2];
  const float* w_ih  = (const float*)d_in[3];
  const float* w_hh  = (const float*)d_in[4];
  const float* b_ih  = (const float*)d_in[5];
  const float* b_hh  = (const float*)d_in[6];
  const float* w_out = (const float*)d_in[7];
  const float* b_out = (const float*)d_in[8];
  const int*   sos   = (const int*)d_in[9];
  float* out = (float*)d_out;

  // workspace carve (~103.7 MB)
  char* ws = (char*)d_ws;
  const size_t XH_SZ = (size_t)B_ * KX * 2;
  const size_t WC_SZ = (size_t)G4 * KX * 2;
  const size_t WO_SZ = (size_t)V_ * H_ * 2;
  const size_t CD_SZ = (size_t)B_ * NC * 8;
  const size_t HC_SZ = (size_t)B_ * H_ * 4;
  u16* X_h[2]; u16* X_m[2]; u16* X_l[2];
  X_h[0] = (u16*)ws; ws += XH_SZ;
  X_m[0] = (u16*)ws; ws += XH_SZ;
  X_l[0] = (u16*)ws; ws += XH_SZ;
  X_h[1] = (u16*)ws; ws += XH_SZ;
  X_m[1] = (u16*)ws; ws += XH_SZ;
  X_l[1] = (u16*)ws; ws += XH_SZ;
  u16* wc_h = (u16*)ws; ws += WC_SZ;
  u16* wc_m = (u16*)ws; ws += WC_SZ;
  u16* wc_l = (u16*)ws; ws += WC_SZ;
  u16* wo   = (u16*)ws; ws += WO_SZ;
  float2* cand = (float2*)ws; ws += CD_SZ;
  float* h_f  = (float*)ws; ws += HC_SZ;
  float* c_f  = (float*)ws; ws += HC_SZ;

  k_zero<<<4000, 256, 0, stream>>>(out);
  k_wout<<<32000, 256, 0, stream>>>(w_out, wo);
  k_wc<<<dim3(6, 4096), 256, 0, stream>>>(w_ih, w_hh, wc_h, wc_m, wc_l);
  k_xh0<<<dim3(6, 128), 256, 0, stream>>>(emb, enc_h, sos, X_h[0], X_m[0], X_l[0]);
  k_c0<<<512, 256, 0, stream>>>(enc_c, c_f);

  for (int t = 1; t < 48; ++t){
    const int d = t & 1, s = d ^ 1;
    k_gates_cell<<<256, 256, 0, stream>>>(X_h[s], X_m[s], X_l[s],
                                          wc_h, wc_m, wc_l, b_ih, b_hh,
                                          c_f, h_f, X_h[d], X_m[d], X_l[d]);
    k_logits<<<250, 256, 0, stream>>>(X_h[d], wo, b_out, out, cand, t);
    if (t < 47)
      k_argmax<<<128, 256, 0, stream>>>(cand, h_f, w_out, b_out, emb,
                                        X_h[d], X_m[d], X_l[d]);
  }
}